// Round 3
// baseline (2072.165 us; speedup 1.0000x reference)
//
#include <hip/hip_runtime.h>
#include <math.h>

#define BB 4
#define TT 2048
#define CC 768
#define HH 12
#define DD 64
// M1 = B*T = 8192

// ---------------------------------------------------------------------------
// fp32 tiled GEMM with bias: out[M,N] = A[M,K] @ W[K,N] + bias[N]
// BM=BN=128, BK=16, 256 threads, 8x8 microtile per thread.
// ---------------------------------------------------------------------------
__global__ __launch_bounds__(256) void gemm_bias_kernel(
    const float* __restrict__ A, const float* __restrict__ W,
    const float* __restrict__ bias, float* __restrict__ Cout,
    int M, int N, int K) {
  constexpr int BM = 128, BN = 128, BK = 16;
  __shared__ float As[BK][BM + 4];   // stored transposed: As[k][m]
  __shared__ float Bs[BK][BN + 4];

  const int tid = threadIdx.x;
  const int brow = blockIdx.y * BM;
  const int bcol = blockIdx.x * BN;
  const int tx = tid & 15;        // 0..15 -> N direction
  const int ty = tid >> 4;        // 0..15 -> M direction

  float acc[8][8];
#pragma unroll
  for (int i = 0; i < 8; ++i)
#pragma unroll
    for (int j = 0; j < 8; ++j) acc[i][j] = 0.f;

  // A-tile load mapping: 128 rows x 16 cols, 2 passes of 64 rows
  const int ar = tid >> 2;            // 0..63
  const int ac = (tid & 3) * 4;       // 0,4,8,12
  // B-tile load mapping: 16 rows x 128 cols, each thread 8 floats
  const int br = tid >> 4;            // 0..15
  const int bc = (tid & 15) * 8;      // 0..120

  for (int k0 = 0; k0 < K; k0 += BK) {
    // load A tile (transposed into LDS)
#pragma unroll
    for (int rr = 0; rr < 2; ++rr) {
      const int r = ar + rr * 64;
      const float4 v = *reinterpret_cast<const float4*>(
          &A[(size_t)(brow + r) * K + k0 + ac]);
      As[ac + 0][r] = v.x;
      As[ac + 1][r] = v.y;
      As[ac + 2][r] = v.z;
      As[ac + 3][r] = v.w;
    }
    // load B tile
    {
      const float4 b0 = *reinterpret_cast<const float4*>(
          &W[(size_t)(k0 + br) * N + bcol + bc]);
      const float4 b1 = *reinterpret_cast<const float4*>(
          &W[(size_t)(k0 + br) * N + bcol + bc + 4]);
      *reinterpret_cast<float4*>(&Bs[br][bc]) = b0;
      *reinterpret_cast<float4*>(&Bs[br][bc + 4]) = b1;
    }
    __syncthreads();

#pragma unroll
    for (int kk = 0; kk < BK; ++kk) {
      float a[8], b[8];
      *reinterpret_cast<float4*>(&a[0]) =
          *reinterpret_cast<const float4*>(&As[kk][ty * 8]);
      *reinterpret_cast<float4*>(&a[4]) =
          *reinterpret_cast<const float4*>(&As[kk][ty * 8 + 4]);
      *reinterpret_cast<float4*>(&b[0]) =
          *reinterpret_cast<const float4*>(&Bs[kk][tx * 8]);
      *reinterpret_cast<float4*>(&b[4]) =
          *reinterpret_cast<const float4*>(&Bs[kk][tx * 8 + 4]);
#pragma unroll
      for (int i = 0; i < 8; ++i)
#pragma unroll
        for (int j = 0; j < 8; ++j) acc[i][j] += a[i] * b[j];
    }
    __syncthreads();
  }

  // epilogue with bias
  float bv[8];
#pragma unroll
  for (int j = 0; j < 8; ++j) bv[j] = bias[bcol + tx * 8 + j];
#pragma unroll
  for (int i = 0; i < 8; ++i) {
    const size_t row = (size_t)(brow + ty * 8 + i);
    float4 o0, o1;
    o0.x = acc[i][0] + bv[0]; o0.y = acc[i][1] + bv[1];
    o0.z = acc[i][2] + bv[2]; o0.w = acc[i][3] + bv[3];
    o1.x = acc[i][4] + bv[4]; o1.y = acc[i][5] + bv[5];
    o1.z = acc[i][6] + bv[6]; o1.w = acc[i][7] + bv[7];
    *reinterpret_cast<float4*>(&Cout[row * N + bcol + tx * 8]) = o0;
    *reinterpret_cast<float4*>(&Cout[row * N + bcol + tx * 8 + 4]) = o1;
  }
}

// ---------------------------------------------------------------------------
// Flash attention (causal), fp32. One query per thread, K/V tiles in LDS.
// qkv layout: [B, T, 3*C] with per-row [3H, D]: q heads 0..11, k 12..23, v 24..35.
// y layout: [B, T, C] with per-row [H, D].
// ---------------------------------------------------------------------------
__global__ __launch_bounds__(256) void attn_kernel(
    const float* __restrict__ qkv, float* __restrict__ y) {
  constexpr int KT = 64;
  __shared__ float Ks[KT][DD];
  __shared__ float Vs[KT][DD];

  const int bh = blockIdx.y;
  const int b = bh / HH, h = bh % HH;
  const int q = blockIdx.x * 256 + threadIdx.x;
  const float scale = 0.125f;  // 1/sqrt(64)
  const size_t rstride = 3 * CC;

  const float* qrow = qkv + ((size_t)b * TT + q) * rstride + h * DD;
  float Q[DD];
#pragma unroll
  for (int d = 0; d < DD; d += 4) {
    const float4 v = *reinterpret_cast<const float4*>(qrow + d);
    Q[d] = v.x * scale; Q[d + 1] = v.y * scale;
    Q[d + 2] = v.z * scale; Q[d + 3] = v.w * scale;
  }
  float O[DD];
#pragma unroll
  for (int d = 0; d < DD; ++d) O[d] = 0.f;
  float m = -1e30f, l = 0.f;

  const float* kbase = qkv + ((size_t)b * TT) * rstride + (HH + h) * DD;
  const float* vbase = qkv + ((size_t)b * TT) * rstride + (2 * HH + h) * DD;
  const int kv_end = blockIdx.x * 256 + 256;

  const int lr = threadIdx.x >> 2;         // 0..63 row to load
  const int lc = (threadIdx.x & 3) * 16;   // 0,16,32,48

  for (int kv0 = 0; kv0 < kv_end; kv0 += KT) {
    __syncthreads();
    {
      const float* kr = kbase + (size_t)(kv0 + lr) * rstride + lc;
      const float* vr = vbase + (size_t)(kv0 + lr) * rstride + lc;
#pragma unroll
      for (int i = 0; i < 16; i += 4) {
        *reinterpret_cast<float4*>(&Ks[lr][lc + i]) =
            *reinterpret_cast<const float4*>(kr + i);
        *reinterpret_cast<float4*>(&Vs[lr][lc + i]) =
            *reinterpret_cast<const float4*>(vr + i);
      }
    }
    __syncthreads();

    const int jmax = min(KT, q - kv0 + 1);
    for (int j = 0; j < jmax; ++j) {
      float s = 0.f;
#pragma unroll
      for (int d = 0; d < DD; d += 4) {
        const float4 k4 = *reinterpret_cast<const float4*>(&Ks[j][d]);
        s += Q[d] * k4.x + Q[d + 1] * k4.y + Q[d + 2] * k4.z + Q[d + 3] * k4.w;
      }
      const float m_new = fmaxf(m, s);
      const float alpha = __expf(m - m_new);
      const float p = __expf(s - m_new);
      l = l * alpha + p;
#pragma unroll
      for (int d = 0; d < DD; d += 4) {
        const float4 v4 = *reinterpret_cast<const float4*>(&Vs[j][d]);
        O[d]     = O[d]     * alpha + p * v4.x;
        O[d + 1] = O[d + 1] * alpha + p * v4.y;
        O[d + 2] = O[d + 2] * alpha + p * v4.z;
        O[d + 3] = O[d + 3] * alpha + p * v4.w;
      }
      m = m_new;
    }
  }

  const float inv_l = 1.f / l;
  float* yrow = y + ((size_t)b * TT + q) * CC + h * DD;
#pragma unroll
  for (int d = 0; d < DD; d += 4) {
    float4 o;
    o.x = O[d] * inv_l; o.y = O[d + 1] * inv_l;
    o.z = O[d + 2] * inv_l; o.w = O[d + 3] * inv_l;
    *reinterpret_cast<float4*>(yrow + d) = o;
  }
}

extern "C" void kernel_launch(void* const* d_in, const int* in_sizes, int n_in,
                              void* d_out, int out_size, void* d_ws, size_t ws_size,
                              hipStream_t stream) {
  const float* x      = (const float*)d_in[0];
  // d_in[1] is the bool causal mask; causality is implemented directly.
  const float* W_attn = (const float*)d_in[2];
  const float* b_attn = (const float*)d_in[3];
  const float* W_proj = (const float*)d_in[4];
  const float* b_proj = (const float*)d_in[5];
  float* out = (float*)d_out;

  const int M = BB * TT;       // 8192
  float* qkv = (float*)d_ws;                       // [8192, 2304]
  float* yws = qkv + (size_t)M * (3 * CC);         // [8192, 768]

  // qkv = x @ W_attn + b_attn
  gemm_bias_kernel<<<dim3((3 * CC) / 128, M / 128), 256, 0, stream>>>(
      x, W_attn, b_attn, qkv, M, 3 * CC, CC);

  // flash attention -> yws [B,T,C]
  attn_kernel<<<dim3(TT / 256, BB * HH), 256, 0, stream>>>(qkv, yws);

  // out = yws @ W_proj + b_proj
  gemm_bias_kernel<<<dim3(CC / 128, M / 128), 256, 0, stream>>>(
      yws, W_proj, b_proj, out, M, CC, CC);
}

// Round 4
// 787.081 us; speedup vs baseline: 2.6327x; 2.6327x over previous
//
#include <hip/hip_runtime.h>
#include <math.h>

#define BB 4
#define TT 2048
#define CC 768
#define HH 12
#define DD 64
#define RS (3 * CC)

typedef __bf16 bf16x8 __attribute__((ext_vector_type(8)));
typedef float f32x4 __attribute__((ext_vector_type(4)));

union U8 { bf16x8 v; unsigned short u[8]; };

__device__ __forceinline__ unsigned short f2bf(float f) {
  union { float f; unsigned u; } x; x.f = f;
  unsigned r = x.u + 0x7fffu + ((x.u >> 16) & 1u);
  return (unsigned short)(r >> 16);
}

// ---------------------------------------------------------------------------
// fp32 tiled GEMM with bias: out[M,N] = A[M,K] @ W[K,N] + bias[N]
// (unchanged from R0 baseline — ~320 us combined; next round's target)
// ---------------------------------------------------------------------------
__global__ __launch_bounds__(256) void gemm_bias_kernel(
    const float* __restrict__ A, const float* __restrict__ W,
    const float* __restrict__ bias, float* __restrict__ Cout,
    int M, int N, int K) {
  constexpr int BM = 128, BN = 128, BK = 16;
  __shared__ float As[BK][BM + 4];
  __shared__ float Bs[BK][BN + 4];

  const int tid = threadIdx.x;
  const int brow = blockIdx.y * BM;
  const int bcol = blockIdx.x * BN;
  const int tx = tid & 15;
  const int ty = tid >> 4;

  float acc[8][8];
#pragma unroll
  for (int i = 0; i < 8; ++i)
#pragma unroll
    for (int j = 0; j < 8; ++j) acc[i][j] = 0.f;

  const int ar = tid >> 2;
  const int ac = (tid & 3) * 4;
  const int br = tid >> 4;
  const int bc = (tid & 15) * 8;

  for (int k0 = 0; k0 < K; k0 += BK) {
#pragma unroll
    for (int rr = 0; rr < 2; ++rr) {
      const int r = ar + rr * 64;
      const float4 v = *reinterpret_cast<const float4*>(
          &A[(size_t)(brow + r) * K + k0 + ac]);
      As[ac + 0][r] = v.x;
      As[ac + 1][r] = v.y;
      As[ac + 2][r] = v.z;
      As[ac + 3][r] = v.w;
    }
    {
      const float4 b0 = *reinterpret_cast<const float4*>(
          &W[(size_t)(k0 + br) * N + bcol + bc]);
      const float4 b1 = *reinterpret_cast<const float4*>(
          &W[(size_t)(k0 + br) * N + bcol + bc + 4]);
      *reinterpret_cast<float4*>(&Bs[br][bc]) = b0;
      *reinterpret_cast<float4*>(&Bs[br][bc + 4]) = b1;
    }
    __syncthreads();

#pragma unroll
    for (int kk = 0; kk < BK; ++kk) {
      float a[8], b[8];
      *reinterpret_cast<float4*>(&a[0]) =
          *reinterpret_cast<const float4*>(&As[kk][ty * 8]);
      *reinterpret_cast<float4*>(&a[4]) =
          *reinterpret_cast<const float4*>(&As[kk][ty * 8 + 4]);
      *reinterpret_cast<float4*>(&b[0]) =
          *reinterpret_cast<const float4*>(&Bs[kk][tx * 8]);
      *reinterpret_cast<float4*>(&b[4]) =
          *reinterpret_cast<const float4*>(&Bs[kk][tx * 8 + 4]);
#pragma unroll
      for (int i = 0; i < 8; ++i)
#pragma unroll
        for (int j = 0; j < 8; ++j) acc[i][j] += a[i] * b[j];
    }
    __syncthreads();
  }

  float bv[8];
#pragma unroll
  for (int j = 0; j < 8; ++j) bv[j] = bias[bcol + tx * 8 + j];
#pragma unroll
  for (int i = 0; i < 8; ++i) {
    const size_t row = (size_t)(brow + ty * 8 + i);
    float4 o0, o1;
    o0.x = acc[i][0] + bv[0]; o0.y = acc[i][1] + bv[1];
    o0.z = acc[i][2] + bv[2]; o0.w = acc[i][3] + bv[3];
    o1.x = acc[i][4] + bv[4]; o1.y = acc[i][5] + bv[5];
    o1.z = acc[i][6] + bv[6]; o1.w = acc[i][7] + bv[7];
    *reinterpret_cast<float4*>(&Cout[row * N + bcol + tx * 8]) = o0;
    *reinterpret_cast<float4*>(&Cout[row * N + bcol + tx * 8 + 4]) = o1;
  }
}

// ---------------------------------------------------------------------------
// bf16 MFMA flash attention (causal).
// Block: 256 thr / 4 waves; 128 queries per block (32 per wave = 2 mreps of 16).
// KV tile = 64 keys staged fp32->bf16 into LDS (K row-major pitch 72; V
// transposed). QK^T and PV via mfma_f32_16x16x32_bf16. Online softmax in
// exp2 domain (0.125*log2e folded into Q). P re-laid out D->A via per-wave LDS.
// MFMA layouts: A row=l&15,k=(l>>4)*8+j; B col=l&15,k same; C/D col=l&15,
// row=(l>>4)*4+reg (m89-verified).
// ---------------------------------------------------------------------------
constexpr int QB = 128;
constexpr int KVT = 64;
constexpr int KP = 72;   // LDS row pitch (ushorts): 144B -> bank-spread, 16B-aligned

__global__ __launch_bounds__(256) void attn_mfma_kernel(
    const float* __restrict__ qkv, float* __restrict__ y) {
  __shared__ unsigned short Ks[KVT][KP];      // [key][d]
  __shared__ unsigned short Vt[DD][KP];       // [d][key] (transposed)
  __shared__ unsigned short Pl[4][32][KP];    // per-wave P: [wave][qrow][key]

  const int tid = threadIdx.x;
  const int w = tid >> 6, l = tid & 63;
  const int lr = l & 15, lg = l >> 4;
  const int bh = blockIdx.y, b = bh / HH, h = bh % HH;
  const int q0 = blockIdx.x * QB;
  const int qw = q0 + w * 32;

  const float* qbase = qkv + (size_t)b * TT * RS + h * DD;
  const float* kbase = qkv + (size_t)b * TT * RS + (HH + h) * DD;
  const float* vbase = qkv + (size_t)b * TT * RS + (2 * HH + h) * DD;

  // Q fragments, scaled by 1/8 * log2(e) (exp2-domain softmax)
  const float qscale = 0.125f * 1.44269504f;
  bf16x8 qf[2][2];
#pragma unroll
  for (int mr = 0; mr < 2; ++mr) {
    const float* qrow = qbase + (size_t)(qw + mr * 16 + lr) * RS;
#pragma unroll
    for (int hf = 0; hf < 2; ++hf) {
      const float* p = qrow + lg * 8 + hf * 32;
      const float4 a = *reinterpret_cast<const float4*>(p);
      const float4 c = *reinterpret_cast<const float4*>(p + 4);
      U8 t;
      t.u[0] = f2bf(a.x * qscale); t.u[1] = f2bf(a.y * qscale);
      t.u[2] = f2bf(a.z * qscale); t.u[3] = f2bf(a.w * qscale);
      t.u[4] = f2bf(c.x * qscale); t.u[5] = f2bf(c.y * qscale);
      t.u[6] = f2bf(c.z * qscale); t.u[7] = f2bf(c.w * qscale);
      qf[mr][hf] = t.v;
    }
  }

  f32x4 O[2][4];
  f32x4 m[2], ls[2];
#pragma unroll
  for (int mr = 0; mr < 2; ++mr) {
    m[mr] = (f32x4)(-3e38f);
    ls[mr] = (f32x4)(0.f);
#pragma unroll
    for (int nb = 0; nb < 4; ++nb) O[mr][nb] = (f32x4)(0.f);
  }

  const int ntiles = q0 / KVT + 2;
  for (int t = 0; t < ntiles; ++t) {
    const int kv0 = t * KVT;
    __syncthreads();
    {  // cooperative stage: 64 keys x 64 dims of K and V(transposed), fp32->bf16
      const int key = tid >> 2, dq = (tid & 3) * 16;
      const float* kr = kbase + (size_t)(kv0 + key) * RS + dq;
      const float* vr = vbase + (size_t)(kv0 + key) * RS + dq;
      float4 k4[4], v4[4];
#pragma unroll
      for (int i = 0; i < 4; ++i) {
        k4[i] = reinterpret_cast<const float4*>(kr)[i];
        v4[i] = reinterpret_cast<const float4*>(vr)[i];
      }
      U8 p0, p1;
      const float* kk = reinterpret_cast<const float*>(k4);
#pragma unroll
      for (int j = 0; j < 8; ++j) { p0.u[j] = f2bf(kk[j]); p1.u[j] = f2bf(kk[8 + j]); }
      *reinterpret_cast<bf16x8*>(&Ks[key][dq]) = p0.v;
      *reinterpret_cast<bf16x8*>(&Ks[key][dq + 8]) = p1.v;
      const float* vv = reinterpret_cast<const float*>(v4);
#pragma unroll
      for (int i = 0; i < 16; ++i) Vt[dq + i][key] = f2bf(vv[i]);
    }
    __syncthreads();

    if (kv0 >= qw + 32) continue;  // wave fully above this tile (barrier at loop top keeps counts equal)

    const int qmax0 = qw + 15, qmax1 = qw + 31;

    // ---- QK^T (K-frags hoisted across mreps) ----
    f32x4 s[2][4];
#pragma unroll
    for (int mr = 0; mr < 2; ++mr)
#pragma unroll
      for (int nb = 0; nb < 4; ++nb) s[mr][nb] = (f32x4)(0.f);
#pragma unroll
    for (int nb = 0; nb < 4; ++nb) {
      const int kmin = kv0 + nb * 16;
      if (kmin > qmax1) continue;                 // fully masked for both mreps
      const bf16x8 k0 = *reinterpret_cast<const bf16x8*>(&Ks[nb * 16 + lr][lg * 8]);
      const bf16x8 k1 = *reinterpret_cast<const bf16x8*>(&Ks[nb * 16 + lr][lg * 8 + 32]);
      if (kmin <= qmax0) {
        s[0][nb] = __builtin_amdgcn_mfma_f32_16x16x32_bf16(qf[0][0], k0, s[0][nb], 0, 0, 0);
        s[0][nb] = __builtin_amdgcn_mfma_f32_16x16x32_bf16(qf[0][1], k1, s[0][nb], 0, 0, 0);
      }
      s[1][nb] = __builtin_amdgcn_mfma_f32_16x16x32_bf16(qf[1][0], k0, s[1][nb], 0, 0, 0);
      s[1][nb] = __builtin_amdgcn_mfma_f32_16x16x32_bf16(qf[1][1], k1, s[1][nb], 0, 0, 0);
    }

    // ---- online softmax per mrep; write P (bf16) to per-wave LDS ----
#pragma unroll
    for (int mr = 0; mr < 2; ++mr) {
      if (kv0 >= qw + mr * 16 + 16) continue;     // this mrep doesn't need the tile
      if (kv0 + KVT > qw + mr * 16) {             // tile touches/crosses diagonal
        const int qrow = qw + mr * 16 + lg * 4;
#pragma unroll
        for (int nb = 0; nb < 4; ++nb) {
          const int key = kv0 + nb * 16 + lr;
#pragma unroll
          for (int r = 0; r < 4; ++r)
            if (key > qrow + r) s[mr][nb][r] = -1e30f;
        }
      }
      f32x4 mx = s[mr][0];
#pragma unroll
      for (int nb = 1; nb < 4; ++nb)
#pragma unroll
        for (int r = 0; r < 4; ++r) mx[r] = fmaxf(mx[r], s[mr][nb][r]);
#pragma unroll
      for (int off = 1; off < 16; off <<= 1)
#pragma unroll
        for (int r = 0; r < 4; ++r) mx[r] = fmaxf(mx[r], __shfl_xor(mx[r], off, 64));
      f32x4 mn, al;
#pragma unroll
      for (int r = 0; r < 4; ++r) {
        mn[r] = fmaxf(m[mr][r], mx[r]);
        al[r] = exp2f(m[mr][r] - mn[r]);
      }
      f32x4 rsum = (f32x4)(0.f);
#pragma unroll
      for (int nb = 0; nb < 4; ++nb)
#pragma unroll
        for (int r = 0; r < 4; ++r) {
          const float p = exp2f(s[mr][nb][r] - mn[r]);
          rsum[r] += p;
          Pl[w][mr * 16 + lg * 4 + r][nb * 16 + lr] = f2bf(p);
        }
#pragma unroll
      for (int off = 1; off < 16; off <<= 1)
#pragma unroll
        for (int r = 0; r < 4; ++r) rsum[r] += __shfl_xor(rsum[r], off, 64);
#pragma unroll
      for (int r = 0; r < 4; ++r) {
        ls[mr][r] = ls[mr][r] * al[r] + rsum[r];
        m[mr][r] = mn[r];
      }
#pragma unroll
      for (int nb = 0; nb < 4; ++nb)
#pragma unroll
        for (int r = 0; r < 4; ++r) O[mr][nb][r] *= al[r];
    }

    // make this wave's P writes visible to its own ds_reads
    asm volatile("s_waitcnt lgkmcnt(0)" ::: "memory");

    // ---- PV (V-frags hoisted across mreps) ----
    {
      const bool mr0 = (kv0 < qw + 16);
      bf16x8 pa10 = *reinterpret_cast<const bf16x8*>(&Pl[w][16 + lr][lg * 8]);
      bf16x8 pa11 = *reinterpret_cast<const bf16x8*>(&Pl[w][16 + lr][lg * 8 + 32]);
      bf16x8 pa00, pa01;
      if (mr0) {
        pa00 = *reinterpret_cast<const bf16x8*>(&Pl[w][lr][lg * 8]);
        pa01 = *reinterpret_cast<const bf16x8*>(&Pl[w][lr][lg * 8 + 32]);
      }
#pragma unroll
      for (int nb = 0; nb < 4; ++nb) {
        const bf16x8 v0 = *reinterpret_cast<const bf16x8*>(&Vt[nb * 16 + lr][lg * 8]);
        const bf16x8 v1 = *reinterpret_cast<const bf16x8*>(&Vt[nb * 16 + lr][lg * 8 + 32]);
        if (mr0) {
          O[0][nb] = __builtin_amdgcn_mfma_f32_16x16x32_bf16(pa00, v0, O[0][nb], 0, 0, 0);
          O[0][nb] = __builtin_amdgcn_mfma_f32_16x16x32_bf16(pa01, v1, O[0][nb], 0, 0, 0);
        }
        O[1][nb] = __builtin_amdgcn_mfma_f32_16x16x32_bf16(pa10, v0, O[1][nb], 0, 0, 0);
        O[1][nb] = __builtin_amdgcn_mfma_f32_16x16x32_bf16(pa11, v1, O[1][nb], 0, 0, 0);
      }
    }
  }

  // ---- epilogue: normalize and store ----
#pragma unroll
  for (int mr = 0; mr < 2; ++mr) {
    f32x4 inv;
#pragma unroll
    for (int r = 0; r < 4; ++r) inv[r] = 1.f / ls[mr][r];
#pragma unroll
    for (int nb = 0; nb < 4; ++nb)
#pragma unroll
      for (int r = 0; r < 4; ++r)
        y[((size_t)b * TT + qw + mr * 16 + lg * 4 + r) * CC + h * DD + nb * 16 + lr] =
            O[mr][nb][r] * inv[r];
  }
}

extern "C" void kernel_launch(void* const* d_in, const int* in_sizes, int n_in,
                              void* d_out, int out_size, void* d_ws, size_t ws_size,
                              hipStream_t stream) {
  const float* x      = (const float*)d_in[0];
  // d_in[1] is the bool causal mask; causality is implemented directly.
  const float* W_attn = (const float*)d_in[2];
  const float* b_attn = (const float*)d_in[3];
  const float* W_proj = (const float*)d_in[4];
  const float* b_proj = (const float*)d_in[5];
  float* out = (float*)d_out;

  const int M = BB * TT;  // 8192
  float* qkv = (float*)d_ws;                   // [8192, 2304]
  float* yws = qkv + (size_t)M * (3 * CC);     // [8192, 768]

  gemm_bias_kernel<<<dim3((3 * CC) / 128, M / 128), 256, 0, stream>>>(
      x, W_attn, b_attn, qkv, M, 3 * CC, CC);

  attn_mfma_kernel<<<dim3(TT / QB, BB * HH), 256, 0, stream>>>(qkv, yws);

  gemm_bias_kernel<<<dim3(CC / 128, M / 128), 256, 0, stream>>>(
      yws, W_proj, b_proj, out, M, CC, CC);
}

// Round 5
// 323.525 us; speedup vs baseline: 6.4050x; 2.4328x over previous
//
#include <hip/hip_runtime.h>
#include <math.h>

#define BB 4
#define TT 2048
#define CC 768
#define HH 12
#define DD 64
#define RS (3 * CC)

typedef __bf16 bf16x8 __attribute__((ext_vector_type(8)));
typedef float f32x4 __attribute__((ext_vector_type(4)));
typedef unsigned short u16x8 __attribute__((ext_vector_type(8)));

union U8 { bf16x8 v; u16x8 s; unsigned short u[8]; };

__device__ __forceinline__ unsigned short f2bf(float f) {
  union { float f; unsigned u; } x; x.f = f;
  unsigned r = x.u + 0x7fffu + ((x.u >> 16) & 1u);
  return (unsigned short)(r >> 16);
}

#define AS1 __attribute__((address_space(1)))
#define AS3 __attribute__((address_space(3)))
__device__ __forceinline__ void gl_lds16(const void* g, void* l) {
  __builtin_amdgcn_global_load_lds((const AS1 unsigned int*)g,
                                   (AS3 unsigned int*)l, 16, 0, 0);
}

// ---------------------------------------------------------------------------
// prep: fp32 -> bf16 elementwise (x -> xb)
// ---------------------------------------------------------------------------
__global__ __launch_bounds__(256) void cvt_bf16_kernel(
    const float* __restrict__ in, unsigned short* __restrict__ out, int n8) {
  int i = blockIdx.x * 256 + threadIdx.x;
  const int stride = gridDim.x * 256;
  for (; i < n8; i += stride) {
    const float4 a = reinterpret_cast<const float4*>(in)[i * 2];
    const float4 b = reinterpret_cast<const float4*>(in)[i * 2 + 1];
    U8 p;
    p.u[0] = f2bf(a.x); p.u[1] = f2bf(a.y); p.u[2] = f2bf(a.z); p.u[3] = f2bf(a.w);
    p.u[4] = f2bf(b.x); p.u[5] = f2bf(b.y); p.u[6] = f2bf(b.z); p.u[7] = f2bf(b.w);
    reinterpret_cast<u16x8*>(out)[i] = p.s;
  }
}

// ---------------------------------------------------------------------------
// prep: W[K][N] fp32 -> Wt[N][K] bf16 (64x64 LDS tile transpose)
// ---------------------------------------------------------------------------
__global__ __launch_bounds__(256) void transpose_cvt_kernel(
    const float* __restrict__ in, unsigned short* __restrict__ out,
    int K, int N) {
  __shared__ float T[64][65];
  const int k0 = blockIdx.y * 64, n0 = blockIdx.x * 64;
  const int tid = threadIdx.x;
  const int ty = tid >> 4, tx4 = (tid & 15) * 4;
#pragma unroll
  for (int i = 0; i < 4; ++i) {
    const int r = ty + i * 16;
    const float4 v = *reinterpret_cast<const float4*>(
        &in[(size_t)(k0 + r) * N + n0 + tx4]);
    T[r][tx4] = v.x; T[r][tx4 + 1] = v.y; T[r][tx4 + 2] = v.z; T[r][tx4 + 3] = v.w;
  }
  __syncthreads();
  const int nrow = tid >> 2, kc = (tid & 3) * 16;
  U8 p0, p1;
#pragma unroll
  for (int i = 0; i < 8; ++i) {
    p0.u[i] = f2bf(T[kc + i][nrow]);
    p1.u[i] = f2bf(T[kc + 8 + i][nrow]);
  }
  unsigned short* o = &out[(size_t)(n0 + nrow) * K + k0 + kc];
  *reinterpret_cast<u16x8*>(o) = p0.s;
  *reinterpret_cast<u16x8*>(o + 8) = p1.s;
}

// ---------------------------------------------------------------------------
// bf16 MFMA GEMM (m97 structure): C[M,N] = A[M,K] @ Bt[N,K]^T + bias
// 128x128 tile, BK=32, 4 waves x (64x64 = 4x4 mfma_16x16x32), global_load_lds.
// OutT: float (fp32 out) or unsigned short (bf16 out).
// ---------------------------------------------------------------------------
template <typename OutT>
__global__ __launch_bounds__(256) void gemm_mfma_kernel(
    const unsigned short* __restrict__ A, const unsigned short* __restrict__ Bt,
    const float* __restrict__ bias, OutT* __restrict__ C,
    int M, int N, int K) {
  __shared__ unsigned short As[128 * 32];
  __shared__ unsigned short Bs[128 * 32];

  const int tid = threadIdx.x;
  const int w = tid >> 6, l = tid & 63, lr = l & 15, lg = l >> 4;
  const int wr = w >> 1, wc = w & 1;
  const int brow = blockIdx.y * 128, bcol = blockIdx.x * 128;

  f32x4 acc[4][4];
#pragma unroll
  for (int i = 0; i < 4; ++i)
#pragma unroll
    for (int j = 0; j < 4; ++j) acc[i][j] = (f32x4)(0.f);

  const int r0 = tid >> 2, c8 = (tid & 3) * 8;
  const unsigned short* gA = A + (size_t)(brow + r0) * K + c8;
  const unsigned short* gB = Bt + (size_t)(bcol + r0) * K + c8;
  unsigned short* lA = As + w * 512;   // per-wave base (1KB per wave)
  unsigned short* lB = Bs + w * 512;

  for (int k0 = 0; k0 < K; k0 += 32) {
    __syncthreads();
    gl_lds16(gA + k0, lA);
    gl_lds16(gA + (size_t)64 * K + k0, lA + 2048);
    gl_lds16(gB + k0, lB);
    gl_lds16(gB + (size_t)64 * K + k0, lB + 2048);
    __syncthreads();

    bf16x8 af[4], bf[4];
#pragma unroll
    for (int mf = 0; mf < 4; ++mf)
      af[mf] = *reinterpret_cast<const bf16x8*>(
          &As[(wr * 64 + mf * 16 + lr) * 32 + lg * 8]);
#pragma unroll
    for (int nf = 0; nf < 4; ++nf)
      bf[nf] = *reinterpret_cast<const bf16x8*>(
          &Bs[(wc * 64 + nf * 16 + lr) * 32 + lg * 8]);
#pragma unroll
    for (int mf = 0; mf < 4; ++mf)
#pragma unroll
      for (int nf = 0; nf < 4; ++nf)
        acc[mf][nf] = __builtin_amdgcn_mfma_f32_16x16x32_bf16(
            af[mf], bf[nf], acc[mf][nf], 0, 0, 0);
  }

#pragma unroll
  for (int nf = 0; nf < 4; ++nf) {
    const int col = bcol + wc * 64 + nf * 16 + lr;
    const float bv = bias[col];
#pragma unroll
    for (int mf = 0; mf < 4; ++mf) {
      const int row0 = brow + wr * 64 + mf * 16 + lg * 4;
#pragma unroll
      for (int r = 0; r < 4; ++r) {
        const float v = acc[mf][nf][r] + bv;
        if constexpr (sizeof(OutT) == 2)
          C[(size_t)(row0 + r) * N + col] = (OutT)f2bf(v);
        else
          C[(size_t)(row0 + r) * N + col] = (OutT)v;
      }
    }
  }
}

// ---------------------------------------------------------------------------
// bf16 MFMA flash attention (causal). qkv is bf16 [B,T,3C]; y out bf16 [B,T,C].
// Same structure as R3 (verified): 4 waves x 32 queries, KV tile 64, padded LDS.
// Softmax scale (1/8 * log2e) applied to S post-MFMA.
// ---------------------------------------------------------------------------
constexpr int QB = 128;
constexpr int KVT = 64;
constexpr int KP = 72;

__global__ __launch_bounds__(256) void attn_mfma_kernel(
    const unsigned short* __restrict__ qkv, unsigned short* __restrict__ y) {
  __shared__ unsigned short Ks[KVT][KP];
  __shared__ unsigned short Vt[DD][KP];
  __shared__ unsigned short Pl[4][32][KP];

  const int tid = threadIdx.x;
  const int w = tid >> 6, l = tid & 63;
  const int lr = l & 15, lg = l >> 4;
  const int bh = blockIdx.y, b = bh / HH, h = bh % HH;
  const int q0 = blockIdx.x * QB;
  const int qw = q0 + w * 32;

  const unsigned short* qbase = qkv + (size_t)b * TT * RS + h * DD;
  const unsigned short* kbase = qkv + (size_t)b * TT * RS + (HH + h) * DD;
  const unsigned short* vbase = qkv + (size_t)b * TT * RS + (2 * HH + h) * DD;

  const float qscale = 0.125f * 1.44269504f;

  bf16x8 qf[2][2];
#pragma unroll
  for (int mr = 0; mr < 2; ++mr) {
    const unsigned short* qrow = qbase + (size_t)(qw + mr * 16 + lr) * RS;
#pragma unroll
    for (int hf = 0; hf < 2; ++hf)
      qf[mr][hf] = *reinterpret_cast<const bf16x8*>(qrow + lg * 8 + hf * 32);
  }

  f32x4 O[2][4];
  f32x4 m[2], ls[2];
#pragma unroll
  for (int mr = 0; mr < 2; ++mr) {
    m[mr] = (f32x4)(-3e38f);
    ls[mr] = (f32x4)(0.f);
#pragma unroll
    for (int nb = 0; nb < 4; ++nb) O[mr][nb] = (f32x4)(0.f);
  }

  const int ntiles = q0 / KVT + 2;
  for (int t = 0; t < ntiles; ++t) {
    const int kv0 = t * KVT;
    __syncthreads();
    {
      const int key = tid >> 2, dq = (tid & 3) * 16;
      const unsigned short* kr = kbase + (size_t)(kv0 + key) * RS + dq;
      const unsigned short* vr = vbase + (size_t)(kv0 + key) * RS + dq;
      const u16x8 k0v = *reinterpret_cast<const u16x8*>(kr);
      const u16x8 k1v = *reinterpret_cast<const u16x8*>(kr + 8);
      *reinterpret_cast<u16x8*>(&Ks[key][dq]) = k0v;
      *reinterpret_cast<u16x8*>(&Ks[key][dq + 8]) = k1v;
      const u16x8 v0 = *reinterpret_cast<const u16x8*>(vr);
      const u16x8 v1 = *reinterpret_cast<const u16x8*>(vr + 8);
#pragma unroll
      for (int i = 0; i < 8; ++i) {
        Vt[dq + i][key] = v0[i];
        Vt[dq + 8 + i][key] = v1[i];
      }
    }
    __syncthreads();

    if (kv0 >= qw + 32) continue;

    const int qmax0 = qw + 15, qmax1 = qw + 31;

    f32x4 s[2][4];
#pragma unroll
    for (int mr = 0; mr < 2; ++mr)
#pragma unroll
      for (int nb = 0; nb < 4; ++nb) s[mr][nb] = (f32x4)(0.f);
#pragma unroll
    for (int nb = 0; nb < 4; ++nb) {
      const int kmin = kv0 + nb * 16;
      if (kmin > qmax1) continue;
      const bf16x8 k0 = *reinterpret_cast<const bf16x8*>(&Ks[nb * 16 + lr][lg * 8]);
      const bf16x8 k1 = *reinterpret_cast<const bf16x8*>(&Ks[nb * 16 + lr][lg * 8 + 32]);
      if (kmin <= qmax0) {
        s[0][nb] = __builtin_amdgcn_mfma_f32_16x16x32_bf16(qf[0][0], k0, s[0][nb], 0, 0, 0);
        s[0][nb] = __builtin_amdgcn_mfma_f32_16x16x32_bf16(qf[0][1], k1, s[0][nb], 0, 0, 0);
      }
      s[1][nb] = __builtin_amdgcn_mfma_f32_16x16x32_bf16(qf[1][0], k0, s[1][nb], 0, 0, 0);
      s[1][nb] = __builtin_amdgcn_mfma_f32_16x16x32_bf16(qf[1][1], k1, s[1][nb], 0, 0, 0);
    }
#pragma unroll
    for (int mr = 0; mr < 2; ++mr)
#pragma unroll
      for (int nb = 0; nb < 4; ++nb)
#pragma unroll
        for (int r = 0; r < 4; ++r) s[mr][nb][r] *= qscale;

#pragma unroll
    for (int mr = 0; mr < 2; ++mr) {
      if (kv0 >= qw + mr * 16 + 16) continue;
      if (kv0 + KVT > qw + mr * 16) {
        const int qrow = qw + mr * 16 + lg * 4;
#pragma unroll
        for (int nb = 0; nb < 4; ++nb) {
          const int key = kv0 + nb * 16 + lr;
#pragma unroll
          for (int r = 0; r < 4; ++r)
            if (key > qrow + r) s[mr][nb][r] = -1e30f;
        }
      }
      f32x4 mx = s[mr][0];
#pragma unroll
      for (int nb = 1; nb < 4; ++nb)
#pragma unroll
        for (int r = 0; r < 4; ++r) mx[r] = fmaxf(mx[r], s[mr][nb][r]);
#pragma unroll
      for (int off = 1; off < 16; off <<= 1)
#pragma unroll
        for (int r = 0; r < 4; ++r) mx[r] = fmaxf(mx[r], __shfl_xor(mx[r], off, 64));
      f32x4 mn, al;
#pragma unroll
      for (int r = 0; r < 4; ++r) {
        mn[r] = fmaxf(m[mr][r], mx[r]);
        al[r] = exp2f(m[mr][r] - mn[r]);
      }
      f32x4 rsum = (f32x4)(0.f);
#pragma unroll
      for (int nb = 0; nb < 4; ++nb)
#pragma unroll
        for (int r = 0; r < 4; ++r) {
          const float p = exp2f(s[mr][nb][r] - mn[r]);
          rsum[r] += p;
          Pl[w][mr * 16 + lg * 4 + r][nb * 16 + lr] = f2bf(p);
        }
#pragma unroll
      for (int off = 1; off < 16; off <<= 1)
#pragma unroll
        for (int r = 0; r < 4; ++r) rsum[r] += __shfl_xor(rsum[r], off, 64);
#pragma unroll
      for (int r = 0; r < 4; ++r) {
        ls[mr][r] = ls[mr][r] * al[r] + rsum[r];
        m[mr][r] = mn[r];
      }
#pragma unroll
      for (int nb = 0; nb < 4; ++nb)
#pragma unroll
        for (int r = 0; r < 4; ++r) O[mr][nb][r] *= al[r];
    }

    asm volatile("s_waitcnt lgkmcnt(0)" ::: "memory");

    {
      const bool mr0 = (kv0 < qw + 16);
      bf16x8 pa10 = *reinterpret_cast<const bf16x8*>(&Pl[w][16 + lr][lg * 8]);
      bf16x8 pa11 = *reinterpret_cast<const bf16x8*>(&Pl[w][16 + lr][lg * 8 + 32]);
      bf16x8 pa00, pa01;
      if (mr0) {
        pa00 = *reinterpret_cast<const bf16x8*>(&Pl[w][lr][lg * 8]);
        pa01 = *reinterpret_cast<const bf16x8*>(&Pl[w][lr][lg * 8 + 32]);
      }
#pragma unroll
      for (int nb = 0; nb < 4; ++nb) {
        const bf16x8 v0 = *reinterpret_cast<const bf16x8*>(&Vt[nb * 16 + lr][lg * 8]);
        const bf16x8 v1 = *reinterpret_cast<const bf16x8*>(&Vt[nb * 16 + lr][lg * 8 + 32]);
        if (mr0) {
          O[0][nb] = __builtin_amdgcn_mfma_f32_16x16x32_bf16(pa00, v0, O[0][nb], 0, 0, 0);
          O[0][nb] = __builtin_amdgcn_mfma_f32_16x16x32_bf16(pa01, v1, O[0][nb], 0, 0, 0);
        }
        O[1][nb] = __builtin_amdgcn_mfma_f32_16x16x32_bf16(pa10, v0, O[1][nb], 0, 0, 0);
        O[1][nb] = __builtin_amdgcn_mfma_f32_16x16x32_bf16(pa11, v1, O[1][nb], 0, 0, 0);
      }
    }
  }

#pragma unroll
  for (int mr = 0; mr < 2; ++mr) {
    f32x4 inv;
#pragma unroll
    for (int r = 0; r < 4; ++r) inv[r] = 1.f / ls[mr][r];
#pragma unroll
    for (int nb = 0; nb < 4; ++nb)
#pragma unroll
      for (int r = 0; r < 4; ++r)
        y[((size_t)b * TT + qw + mr * 16 + lg * 4 + r) * CC + h * DD + nb * 16 + lr] =
            f2bf(O[mr][nb][r] * inv[r]);
  }
}

extern "C" void kernel_launch(void* const* d_in, const int* in_sizes, int n_in,
                              void* d_out, int out_size, void* d_ws, size_t ws_size,
                              hipStream_t stream) {
  const float* x      = (const float*)d_in[0];
  const float* W_attn = (const float*)d_in[2];
  const float* b_attn = (const float*)d_in[3];
  const float* W_proj = (const float*)d_in[4];
  const float* b_proj = (const float*)d_in[5];
  float* out = (float*)d_out;

  const int M = BB * TT;  // 8192
  // workspace layout (bf16 = unsigned short)
  unsigned short* qkvb = (unsigned short*)d_ws;            // [8192][2304]
  unsigned short* xb   = qkvb + (size_t)M * RS;            // [8192][768]
  unsigned short* yb   = xb + (size_t)M * CC;              // [8192][768]
  unsigned short* Wt1  = yb + (size_t)M * CC;              // [2304][768]
  unsigned short* Wt2  = Wt1 + (size_t)RS * CC;            // [768][768]

  // prep
  cvt_bf16_kernel<<<1024, 256, 0, stream>>>(x, xb, M * CC / 8);
  transpose_cvt_kernel<<<dim3(RS / 64, CC / 64), 256, 0, stream>>>(
      W_attn, Wt1, CC, RS);
  transpose_cvt_kernel<<<dim3(CC / 64, CC / 64), 256, 0, stream>>>(
      W_proj, Wt2, CC, CC);

  // qkv = x @ W_attn + b_attn  (bf16 out)
  gemm_mfma_kernel<unsigned short><<<dim3(RS / 128, M / 128), 256, 0, stream>>>(
      xb, Wt1, b_attn, qkvb, M, RS, CC);

  // flash attention -> yb (bf16)
  attn_mfma_kernel<<<dim3(TT / QB, BB * HH), 256, 0, stream>>>(qkvb, yb);

  // out = y @ W_proj + b_proj  (fp32 out)
  gemm_mfma_kernel<float><<<dim3(CC / 128, M / 128), 256, 0, stream>>>(
      yb, Wt2, b_proj, out, M, CC, CC);
}

// Round 6
// 236.912 us; speedup vs baseline: 8.7465x; 1.3656x over previous
//
#include <hip/hip_runtime.h>
#include <math.h>

#define BB 4
#define TT 2048
#define CC 768
#define HH 12
#define DD 64
#define RS (3 * CC)

typedef __bf16 bf16x8 __attribute__((ext_vector_type(8)));
typedef float f32x4 __attribute__((ext_vector_type(4)));
typedef unsigned short u16x8 __attribute__((ext_vector_type(8)));

union U8 { bf16x8 v; u16x8 s; unsigned short u[8]; };

__device__ __forceinline__ unsigned short f2bf(float f) {
  union { float f; unsigned u; } x; x.f = f;
  unsigned r = x.u + 0x7fffu + ((x.u >> 16) & 1u);
  return (unsigned short)(r >> 16);
}

#define AS1 __attribute__((address_space(1)))
#define AS3 __attribute__((address_space(3)))
__device__ __forceinline__ void gl_lds16(const void* g, void* l) {
  __builtin_amdgcn_global_load_lds((const AS1 unsigned int*)g,
                                   (AS3 unsigned int*)l, 16, 0, 0);
}

// ---------------------------------------------------------------------------
// prep: fp32 -> bf16 elementwise (x -> xb)
// ---------------------------------------------------------------------------
__global__ __launch_bounds__(256) void cvt_bf16_kernel(
    const float* __restrict__ in, unsigned short* __restrict__ out, int n8) {
  int i = blockIdx.x * 256 + threadIdx.x;
  const int stride = gridDim.x * 256;
  for (; i < n8; i += stride) {
    const float4 a = reinterpret_cast<const float4*>(in)[i * 2];
    const float4 b = reinterpret_cast<const float4*>(in)[i * 2 + 1];
    U8 p;
    p.u[0] = f2bf(a.x); p.u[1] = f2bf(a.y); p.u[2] = f2bf(a.z); p.u[3] = f2bf(a.w);
    p.u[4] = f2bf(b.x); p.u[5] = f2bf(b.y); p.u[6] = f2bf(b.z); p.u[7] = f2bf(b.w);
    reinterpret_cast<u16x8*>(out)[i] = p.s;
  }
}

// ---------------------------------------------------------------------------
// prep: W[K][N] fp32 -> Wt[N][K] bf16 (64x64 LDS tile transpose)
// ---------------------------------------------------------------------------
__global__ __launch_bounds__(256) void transpose_cvt_kernel(
    const float* __restrict__ in, unsigned short* __restrict__ out,
    int K, int N) {
  __shared__ float T[64][65];
  const int k0 = blockIdx.y * 64, n0 = blockIdx.x * 64;
  const int tid = threadIdx.x;
  const int ty = tid >> 4, tx4 = (tid & 15) * 4;
#pragma unroll
  for (int i = 0; i < 4; ++i) {
    const int r = ty + i * 16;
    const float4 v = *reinterpret_cast<const float4*>(
        &in[(size_t)(k0 + r) * N + n0 + tx4]);
    T[r][tx4] = v.x; T[r][tx4 + 1] = v.y; T[r][tx4 + 2] = v.z; T[r][tx4 + 3] = v.w;
  }
  __syncthreads();
  const int nrow = tid >> 2, kc = (tid & 3) * 16;
  U8 p0, p1;
#pragma unroll
  for (int i = 0; i < 8; ++i) {
    p0.u[i] = f2bf(T[kc + i][nrow]);
    p1.u[i] = f2bf(T[kc + 8 + i][nrow]);
  }
  unsigned short* o = &out[(size_t)(n0 + nrow) * K + k0 + kc];
  *reinterpret_cast<u16x8*>(o) = p0.s;
  *reinterpret_cast<u16x8*>(o + 8) = p1.s;
}

// ---------------------------------------------------------------------------
// bf16 MFMA GEMM (m97 structure): C[M,N] = A[M,K] @ Bt[N,K]^T + bias
// ---------------------------------------------------------------------------
template <typename OutT>
__global__ __launch_bounds__(256) void gemm_mfma_kernel(
    const unsigned short* __restrict__ A, const unsigned short* __restrict__ Bt,
    const float* __restrict__ bias, OutT* __restrict__ C,
    int M, int N, int K) {
  __shared__ unsigned short As[128 * 32];
  __shared__ unsigned short Bs[128 * 32];

  const int tid = threadIdx.x;
  const int w = tid >> 6, l = tid & 63, lr = l & 15, lg = l >> 4;
  const int wr = w >> 1, wc = w & 1;
  const int brow = blockIdx.y * 128, bcol = blockIdx.x * 128;

  f32x4 acc[4][4];
#pragma unroll
  for (int i = 0; i < 4; ++i)
#pragma unroll
    for (int j = 0; j < 4; ++j) acc[i][j] = (f32x4)(0.f);

  const int r0 = tid >> 2, c8 = (tid & 3) * 8;
  const unsigned short* gA = A + (size_t)(brow + r0) * K + c8;
  const unsigned short* gB = Bt + (size_t)(bcol + r0) * K + c8;
  unsigned short* lA = As + w * 512;
  unsigned short* lB = Bs + w * 512;

  for (int k0 = 0; k0 < K; k0 += 32) {
    __syncthreads();
    gl_lds16(gA + k0, lA);
    gl_lds16(gA + (size_t)64 * K + k0, lA + 2048);
    gl_lds16(gB + k0, lB);
    gl_lds16(gB + (size_t)64 * K + k0, lB + 2048);
    __syncthreads();

    bf16x8 af[4], bf[4];
#pragma unroll
    for (int mf = 0; mf < 4; ++mf)
      af[mf] = *reinterpret_cast<const bf16x8*>(
          &As[(wr * 64 + mf * 16 + lr) * 32 + lg * 8]);
#pragma unroll
    for (int nf = 0; nf < 4; ++nf)
      bf[nf] = *reinterpret_cast<const bf16x8*>(
          &Bs[(wc * 64 + nf * 16 + lr) * 32 + lg * 8]);
#pragma unroll
    for (int mf = 0; mf < 4; ++mf)
#pragma unroll
      for (int nf = 0; nf < 4; ++nf)
        acc[mf][nf] = __builtin_amdgcn_mfma_f32_16x16x32_bf16(
            af[mf], bf[nf], acc[mf][nf], 0, 0, 0);
  }

#pragma unroll
  for (int nf = 0; nf < 4; ++nf) {
    const int col = bcol + wc * 64 + nf * 16 + lr;
    const float bv = bias[col];
#pragma unroll
    for (int mf = 0; mf < 4; ++mf) {
      const int row0 = brow + wr * 64 + mf * 16 + lg * 4;
#pragma unroll
      for (int r = 0; r < 4; ++r) {
        const float v = acc[mf][nf][r] + bv;
        if constexpr (sizeof(OutT) == 2)
          C[(size_t)(row0 + r) * N + col] = (OutT)f2bf(v);
        else
          C[(size_t)(row0 + r) * N + col] = (OutT)v;
      }
    }
  }
}

// ---------------------------------------------------------------------------
// bf16 MFMA flash attention (causal) with PAIRED q-groups for load balance.
// Block g handles q-groups g (rows 64g..64g+63) and 31-g. Each wave: mrep0 =
// 16 rows of group g, mrep1 = 16 rows of group 31-g. Staged KV range = high
// group's (32-g tiles) -> uniform ~33 tile-mreps of compute per block.
// Vt stored with octant offset (col = key + (d&48), pitch 112) -> conflict-
// free transpose-staging writes.
// ---------------------------------------------------------------------------
constexpr int KVT = 64;
constexpr int KP = 72;     // K and P pitch (ushorts)
constexpr int VP = 112;    // V pitch (ushorts), octant-offset layout

__global__ __launch_bounds__(256) void attn_mfma_kernel(
    const unsigned short* __restrict__ qkv, unsigned short* __restrict__ y) {
  __shared__ unsigned short Ks[KVT][KP];
  __shared__ unsigned short Vt[DD][VP];
  __shared__ unsigned short Pl[4][32][KP];

  const int tid = threadIdx.x;
  const int w = tid >> 6, l = tid & 63;
  const int lr = l & 15, lg = l >> 4;
  const int bh = blockIdx.y, b = bh / HH, h = bh % HH;
  const int g = blockIdx.x;                       // pair (g, 31-g)
  const int qwm[2] = {g * 64 + w * 16, (31 - g) * 64 + w * 16};
  const int qmax0 = qwm[0] + 15, qmax1 = qwm[1] + 15;

  const unsigned short* qbase = qkv + (size_t)b * TT * RS + h * DD;
  const unsigned short* kbase = qkv + (size_t)b * TT * RS + (HH + h) * DD;
  const unsigned short* vbase = qkv + (size_t)b * TT * RS + (2 * HH + h) * DD;

  const float qscale = 0.125f * 1.44269504f;

  bf16x8 qf[2][2];
#pragma unroll
  for (int mr = 0; mr < 2; ++mr) {
    const unsigned short* qrow = qbase + (size_t)(qwm[mr] + lr) * RS;
#pragma unroll
    for (int hf = 0; hf < 2; ++hf)
      qf[mr][hf] = *reinterpret_cast<const bf16x8*>(qrow + lg * 8 + hf * 32);
  }

  f32x4 O[2][4];
  f32x4 m[2], ls[2];
#pragma unroll
  for (int mr = 0; mr < 2; ++mr) {
    m[mr] = (f32x4)(-3e38f);
    ls[mr] = (f32x4)(0.f);
#pragma unroll
    for (int nb = 0; nb < 4; ++nb) O[mr][nb] = (f32x4)(0.f);
  }

  const int ntiles = 32 - g;
  for (int t = 0; t < ntiles; ++t) {
    const int kv0 = t * KVT;
    __syncthreads();
    {
      const int key = tid >> 2, dq = (tid & 3) * 16;
      const unsigned short* kr = kbase + (size_t)(kv0 + key) * RS + dq;
      const unsigned short* vr = vbase + (size_t)(kv0 + key) * RS + dq;
      const u16x8 k0v = *reinterpret_cast<const u16x8*>(kr);
      const u16x8 k1v = *reinterpret_cast<const u16x8*>(kr + 8);
      *reinterpret_cast<u16x8*>(&Ks[key][dq]) = k0v;
      *reinterpret_cast<u16x8*>(&Ks[key][dq + 8]) = k1v;
      const u16x8 v0 = *reinterpret_cast<const u16x8*>(vr);
      const u16x8 v1 = *reinterpret_cast<const u16x8*>(vr + 8);
      const int vcol = key + dq;   // octant offset: (d & 48) == dq for d in [dq, dq+16)
#pragma unroll
      for (int i = 0; i < 8; ++i) {
        Vt[dq + i][vcol] = v0[i];
        Vt[dq + 8 + i][vcol] = v1[i];
      }
    }
    __syncthreads();

    // ---- QK^T: mrep1 (high group) always active; mrep0 while in range ----
    const bool act0 = (kv0 < qwm[0] + 16);
    f32x4 s[2][4];
#pragma unroll
    for (int mr = 0; mr < 2; ++mr)
#pragma unroll
      for (int nb = 0; nb < 4; ++nb) s[mr][nb] = (f32x4)(0.f);
#pragma unroll
    for (int nb = 0; nb < 4; ++nb) {
      const int kmin = kv0 + nb * 16;
      if (kmin > qmax1) continue;
      const bf16x8 k0 = *reinterpret_cast<const bf16x8*>(&Ks[nb * 16 + lr][lg * 8]);
      const bf16x8 k1 = *reinterpret_cast<const bf16x8*>(&Ks[nb * 16 + lr][lg * 8 + 32]);
      if (act0 && kmin <= qmax0) {
        s[0][nb] = __builtin_amdgcn_mfma_f32_16x16x32_bf16(qf[0][0], k0, s[0][nb], 0, 0, 0);
        s[0][nb] = __builtin_amdgcn_mfma_f32_16x16x32_bf16(qf[0][1], k1, s[0][nb], 0, 0, 0);
      }
      s[1][nb] = __builtin_amdgcn_mfma_f32_16x16x32_bf16(qf[1][0], k0, s[1][nb], 0, 0, 0);
      s[1][nb] = __builtin_amdgcn_mfma_f32_16x16x32_bf16(qf[1][1], k1, s[1][nb], 0, 0, 0);
    }

    // ---- online softmax per mrep; write P (bf16) to per-wave LDS ----
#pragma unroll
    for (int mr = 0; mr < 2; ++mr) {
      if (mr == 0 && !act0) continue;
#pragma unroll
      for (int nb = 0; nb < 4; ++nb)
#pragma unroll
        for (int r = 0; r < 4; ++r) s[mr][nb][r] *= qscale;
      if (kv0 + KVT > qwm[mr]) {   // tile touches/crosses diagonal
        const int qrow = qwm[mr] + lg * 4;
#pragma unroll
        for (int nb = 0; nb < 4; ++nb) {
          const int key = kv0 + nb * 16 + lr;
#pragma unroll
          for (int r = 0; r < 4; ++r)
            if (key > qrow + r) s[mr][nb][r] = -1e30f;
        }
      }
      f32x4 mx = s[mr][0];
#pragma unroll
      for (int nb = 1; nb < 4; ++nb)
#pragma unroll
        for (int r = 0; r < 4; ++r) mx[r] = fmaxf(mx[r], s[mr][nb][r]);
#pragma unroll
      for (int off = 1; off < 16; off <<= 1)
#pragma unroll
        for (int r = 0; r < 4; ++r) mx[r] = fmaxf(mx[r], __shfl_xor(mx[r], off, 64));
      f32x4 mn, al;
#pragma unroll
      for (int r = 0; r < 4; ++r) {
        mn[r] = fmaxf(m[mr][r], mx[r]);
        al[r] = exp2f(m[mr][r] - mn[r]);
      }
      f32x4 rsum = (f32x4)(0.f);
#pragma unroll
      for (int nb = 0; nb < 4; ++nb)
#pragma unroll
        for (int r = 0; r < 4; ++r) {
          const float p = exp2f(s[mr][nb][r] - mn[r]);
          rsum[r] += p;
          Pl[w][mr * 16 + lg * 4 + r][nb * 16 + lr] = f2bf(p);
        }
#pragma unroll
      for (int off = 1; off < 16; off <<= 1)
#pragma unroll
        for (int r = 0; r < 4; ++r) rsum[r] += __shfl_xor(rsum[r], off, 64);
#pragma unroll
      for (int r = 0; r < 4; ++r) {
        ls[mr][r] = ls[mr][r] * al[r] + rsum[r];
        m[mr][r] = mn[r];
      }
#pragma unroll
      for (int nb = 0; nb < 4; ++nb)
#pragma unroll
        for (int r = 0; r < 4; ++r) O[mr][nb][r] *= al[r];
    }

    asm volatile("s_waitcnt lgkmcnt(0)" ::: "memory");

    // ---- PV (V-frags shared across mreps) ----
    {
      bf16x8 pa10 = *reinterpret_cast<const bf16x8*>(&Pl[w][16 + lr][lg * 8]);
      bf16x8 pa11 = *reinterpret_cast<const bf16x8*>(&Pl[w][16 + lr][lg * 8 + 32]);
      bf16x8 pa00, pa01;
      if (act0) {
        pa00 = *reinterpret_cast<const bf16x8*>(&Pl[w][lr][lg * 8]);
        pa01 = *reinterpret_cast<const bf16x8*>(&Pl[w][lr][lg * 8 + 32]);
      }
#pragma unroll
      for (int nb = 0; nb < 4; ++nb) {
        const int oct = nb * 16;   // (d & 48) = 16*nb for d = nb*16+lr
        const bf16x8 v0 = *reinterpret_cast<const bf16x8*>(&Vt[nb * 16 + lr][lg * 8 + oct]);
        const bf16x8 v1 = *reinterpret_cast<const bf16x8*>(&Vt[nb * 16 + lr][lg * 8 + 32 + oct]);
        if (act0) {
          O[0][nb] = __builtin_amdgcn_mfma_f32_16x16x32_bf16(pa00, v0, O[0][nb], 0, 0, 0);
          O[0][nb] = __builtin_amdgcn_mfma_f32_16x16x32_bf16(pa01, v1, O[0][nb], 0, 0, 0);
        }
        O[1][nb] = __builtin_amdgcn_mfma_f32_16x16x32_bf16(pa10, v0, O[1][nb], 0, 0, 0);
        O[1][nb] = __builtin_amdgcn_mfma_f32_16x16x32_bf16(pa11, v1, O[1][nb], 0, 0, 0);
      }
    }
  }

#pragma unroll
  for (int mr = 0; mr < 2; ++mr) {
    f32x4 inv;
#pragma unroll
    for (int r = 0; r < 4; ++r) inv[r] = 1.f / ls[mr][r];
#pragma unroll
    for (int nb = 0; nb < 4; ++nb)
#pragma unroll
      for (int r = 0; r < 4; ++r)
        y[((size_t)b * TT + qwm[mr] + lg * 4 + r) * CC + h * DD + nb * 16 + lr] =
            f2bf(O[mr][nb][r] * inv[r]);
  }
}

extern "C" void kernel_launch(void* const* d_in, const int* in_sizes, int n_in,
                              void* d_out, int out_size, void* d_ws, size_t ws_size,
                              hipStream_t stream) {
  const float* x      = (const float*)d_in[0];
  const float* W_attn = (const float*)d_in[2];
  const float* b_attn = (const float*)d_in[3];
  const float* W_proj = (const float*)d_in[4];
  const float* b_proj = (const float*)d_in[5];
  float* out = (float*)d_out;

  const int M = BB * TT;  // 8192
  unsigned short* qkvb = (unsigned short*)d_ws;            // [8192][2304]
  unsigned short* xb   = qkvb + (size_t)M * RS;            // [8192][768]
  unsigned short* yb   = xb + (size_t)M * CC;              // [8192][768]
  unsigned short* Wt1  = yb + (size_t)M * CC;              // [2304][768]
  unsigned short* Wt2  = Wt1 + (size_t)RS * CC;            // [768][768]

  cvt_bf16_kernel<<<1024, 256, 0, stream>>>(x, xb, M * CC / 8);
  transpose_cvt_kernel<<<dim3(RS / 64, CC / 64), 256, 0, stream>>>(
      W_attn, Wt1, CC, RS);
  transpose_cvt_kernel<<<dim3(CC / 64, CC / 64), 256, 0, stream>>>(
      W_proj, Wt2, CC, CC);

  gemm_mfma_kernel<unsigned short><<<dim3(RS / 128, M / 128), 256, 0, stream>>>(
      xb, Wt1, b_attn, qkvb, M, RS, CC);

  // paired-causal flash attention: 16 pair-blocks x 48 heads
  attn_mfma_kernel<<<dim3(16, BB * HH), 256, 0, stream>>>(qkvb, yb);

  gemm_mfma_kernel<float><<<dim3(CC / 128, M / 128), 256, 0, stream>>>(
      yb, Wt2, b_proj, out, M, CC, CC);
}